// Round 4
// baseline (779.104 us; speedup 1.0000x reference)
//
#include <hip/hip_runtime.h>
#include <stdint.h>

#define NN3 262144
#define NN2 65536
#define NN1 16384
#define NBLK 1024

typedef __attribute__((ext_vector_type(8))) __bf16 bf16x8;
typedef __attribute__((ext_vector_type(4))) float floatx4;

static __device__ __forceinline__ float bf2f(unsigned short u) {
    union { unsigned int i; float f; } v; v.i = ((unsigned int)u) << 16; return v.f;
}
static __device__ __forceinline__ unsigned short f2bf(float f) {
    union { float f; unsigned int i; } v; v.f = f;
    unsigned int x = v.i;
    return (unsigned short)((x + 0x7fffu + ((x >> 16) & 1u)) >> 16);
}
static __device__ __forceinline__ bf16x8 zero_bf16x8() {
    bf16x8 z;
#pragma unroll
    for (int i = 0; i < 8; ++i) z[i] = (__bf16)0.0f;
    return z;
}

// ---------------- barrier init (separate tiny launch; ws is poisoned 0xAA) ----------------
__global__ void init_barrier_kernel(int* bar) { bar[0] = 0; bar[16] = 0; }

// ---------------- device-scope grid barrier (all NBLK blocks co-resident) ----------------
static __device__ __forceinline__ void grid_barrier(int* cnt, int* gen) {
    __syncthreads();
    if (threadIdx.x == 0) {
        // release: make this block's prior global writes visible at device scope
        __builtin_amdgcn_fence(__ATOMIC_RELEASE, "agent");
        int g = __hip_atomic_load(gen, __ATOMIC_RELAXED, __HIP_MEMORY_SCOPE_AGENT);
        int prev = __hip_atomic_fetch_add(cnt, 1, __ATOMIC_RELAXED, __HIP_MEMORY_SCOPE_AGENT);
        if (prev == (int)gridDim.x - 1) {
            __hip_atomic_store(cnt, 0, __ATOMIC_RELAXED, __HIP_MEMORY_SCOPE_AGENT);
            __hip_atomic_store(gen, g + 1, __ATOMIC_RELAXED, __HIP_MEMORY_SCOPE_AGENT);
        } else {
            while (__hip_atomic_load(gen, __ATOMIC_RELAXED, __HIP_MEMORY_SCOPE_AGENT) == g)
                __builtin_amdgcn_s_sleep(1);
        }
        // acquire: invalidate stale cached lines before consuming other blocks' writes
        __builtin_amdgcn_fence(__ATOMIC_ACQUIRE, "agent");
    }
    __syncthreads();
}

// ---------------- stage bodies ----------------
static __device__ __forceinline__ void enc1pool_body(
    const float* __restrict__ feat, const int* __restrict__ neigh,
    const float* __restrict__ w, const float* __restrict__ b,
    unsigned short* __restrict__ x7p, int* nsh, float* wsf)
{
    int t = threadIdx.x;
    for (int blk = blockIdx.x; blk < NN3 / 256; blk += gridDim.x) {
        int base = blk * 256;
        if (t < 144) wsf[t] = w[t];
        if (t >= 144 && t < 160) wsf[t] = b[t - 144];
        for (int e = t; e < 2304; e += 256) nsh[e] = neigh[(size_t)base * 9 + e];
        __syncthreads();
        float f[9];
#pragma unroll
        for (int k = 0; k < 9; ++k) { int j = nsh[t * 9 + k]; f[k] = (j < 0) ? 0.0f : feat[j]; }
        float v[16];
#pragma unroll
        for (int co = 0; co < 16; ++co) {
            float a = wsf[144 + co];
#pragma unroll
            for (int k = 0; k < 9; ++k) a += f[k] * wsf[co * 9 + k];
            v[co] = fmaxf(a, 0.0f);
        }
#pragma unroll
        for (int co = 0; co < 16; ++co) {
            v[co] = fmaxf(v[co], __shfl_xor(v[co], 1));
            v[co] = fmaxf(v[co], __shfl_xor(v[co], 2));
        }
        if ((t & 3) == 0) {
            unsigned int ov[8];
#pragma unroll
            for (int h = 0; h < 8; ++h)
                ov[h] = (unsigned int)f2bf(v[2 * h]) | (((unsigned int)f2bf(v[2 * h + 1])) << 16);
            uint4* dst = (uint4*)(x7p + (size_t)((base + t) >> 2) * 16);
            dst[0] = make_uint4(ov[0], ov[1], ov[2], ov[3]);
            dst[1] = make_uint4(ov[4], ov[5], ov[6], ov[7]);
        }
        __syncthreads();
    }
}

template <int CIN, int COUT, bool SHIFT, bool POOL>
static __device__ __forceinline__ void conv_body(
    const unsigned short* __restrict__ src, const int* __restrict__ neigh,
    const unsigned short* __restrict__ wb, const float* __restrict__ bias,
    unsigned short* __restrict__ dst, int* nsh, int nblk)
{
    constexpr int K  = 9 * CIN;
    constexpr int KT = (K + 31) / 32;
    constexpr int NT = COUT / 16;
    int t = threadIdx.x;
    int lane = t & 63;
    int wave = t >> 6;
    int m    = lane & 15;
    int quad = lane >> 4;
    int mrow = wave * 16 + m;
    for (int blk = blockIdx.x; blk < nblk; blk += gridDim.x) {
        int rowbase = blk * 64;
        for (int e = t; e < 576; e += 256) {
            int j = neigh[(size_t)rowbase * 9 + e];
            if (SHIFT) j = (j < 0) ? -1 : (j >> 2);
            nsh[e] = j;
        }
        __syncthreads();
        floatx4 acc[NT];
#pragma unroll
        for (int n = 0; n < NT; ++n) acc[n] = (floatx4){0.f, 0.f, 0.f, 0.f};
#pragma unroll
        for (int kt = 0; kt < KT; ++kt) {
            int k0 = kt * 32 + quad * 8;
            bf16x8 a = zero_bf16x8();
            if (k0 < K) {
                int nb = k0 / CIN;
                int ci = k0 % CIN;
                int j  = nsh[mrow * 9 + nb];
                if (j >= 0) a = *(const bf16x8*)(src + (size_t)j * CIN + ci);
            }
#pragma unroll
            for (int n = 0; n < NT; ++n) {
                bf16x8 bfrag = zero_bf16x8();
                if (k0 < K) bfrag = *(const bf16x8*)(wb + (size_t)(n * 16 + m) * K + k0);
                acc[n] = __builtin_amdgcn_mfma_f32_16x16x32_bf16(a, bfrag, acc[n], 0, 0, 0);
            }
        }
        if (POOL) {
            int p = (rowbase >> 2) + wave * 4 + quad;
#pragma unroll
            for (int n = 0; n < NT; ++n) {
                int cout = n * 16 + m;
                float vm = fmaxf(fmaxf(acc[n][0], acc[n][1]), fmaxf(acc[n][2], acc[n][3]));
                float v  = fmaxf(vm + bias[cout], 0.0f);
                dst[(size_t)p * COUT + cout] = f2bf(v);
            }
        } else {
            int grow = rowbase + wave * 16 + quad * 4;
#pragma unroll
            for (int n = 0; n < NT; ++n) {
                int cout = n * 16 + m;
                float bv = bias[cout];
#pragma unroll
                for (int r = 0; r < 4; ++r) {
                    float v = fmaxf(acc[n][r] + bv, 0.0f);
                    dst[(size_t)(grow + r) * COUT + cout] = f2bf(v);
                }
            }
        }
        __syncthreads();
    }
}

static __device__ __forceinline__ float dot2(unsigned int u, const float* w) {
    return bf2f((unsigned short)(u & 0xffffu)) * w[0] + bf2f((unsigned short)(u >> 16)) * w[1];
}

static __device__ __forceinline__ void head_body(
    const unsigned short* __restrict__ x, const int* __restrict__ neigh,
    const float* __restrict__ w, const float* __restrict__ b, float* __restrict__ out,
    int* nsh, float* wsf)
{
    int t = threadIdx.x;
    for (int blk = blockIdx.x; blk < NN3 / 256; blk += gridDim.x) {
        int base = blk * 256;
        if (t < 144) wsf[t] = w[t];
        for (int e = t; e < 2304; e += 256) nsh[e] = neigh[(size_t)base * 9 + e];
        __syncthreads();
        float acc = b[0];
#pragma unroll
        for (int k = 0; k < 9; ++k) {
            int j = nsh[t * 9 + k];
            if (j >= 0) {
                const uint4* r = (const uint4*)(x + (size_t)j * 16);
                uint4 r0 = r[0], r1 = r[1];
                const float* wp = &wsf[k * 16];
                acc += dot2(r0.x, wp)     + dot2(r0.y, wp + 2)  + dot2(r0.z, wp + 4)  + dot2(r0.w, wp + 6);
                acc += dot2(r1.x, wp + 8) + dot2(r1.y, wp + 10) + dot2(r1.z, wp + 12) + dot2(r1.w, wp + 14);
            }
        }
        out[base + t] = acc;
        __syncthreads();
    }
}

// ---------------- fused persistent kernel ----------------
__global__ __launch_bounds__(256, 4) void fused_kernel(
    const float* __restrict__ feat,
    const int* __restrict__ n3, const int* __restrict__ n2, const int* __restrict__ n1,
    const float* __restrict__ w_enc1, const float* __restrict__ b_enc1,
    const float* __restrict__ w_enc2, const float* __restrict__ b_enc2,
    const float* __restrict__ w_enc3, const float* __restrict__ b_enc3,
    const float* __restrict__ w_dec1, const float* __restrict__ b_dec1,
    const float* __restrict__ w_dec2, const float* __restrict__ b_dec2,
    const float* __restrict__ w_head, const float* __restrict__ b_head,
    unsigned short* wb_enc2, unsigned short* wb_enc3,
    unsigned short* wb_dec1, unsigned short* wb_dec2,
    unsigned short* x7p, unsigned short* x6p, unsigned short* x6,
    unsigned short* x7dec, unsigned short* x8dec,
    float* out, int* bar)
{
    __shared__ int nsh[2304];
    __shared__ float wsf[160];
    int* cnt = bar;
    int* gen = bar + 16;

    // Stage A: weight fp32->bf16 prep (46080 elems, first 180 blocks) + enc1+pool1
    {
        int t = blockIdx.x * 256 + threadIdx.x;
        if (t < 4608) wb_enc2[t] = f2bf(w_enc2[t]);
        else {
            t -= 4608;
            if (t < 18432) wb_enc3[t] = f2bf(w_enc3[t]);
            else {
                t -= 18432;
                if (t < 18432) wb_dec1[t] = f2bf(w_dec1[t]);
                else { t -= 18432; if (t < 4608) wb_dec2[t] = f2bf(w_dec2[t]); }
            }
        }
    }
    enc1pool_body(feat, n3, w_enc1, b_enc1, x7p, nsh, wsf);
    grid_barrier(cnt, gen);
    // Stage B: enc2 + pool2
    conv_body<16, 32, false, true>(x7p, n2, wb_enc2, b_enc2, x6p, nsh, NN2 / 64);
    grid_barrier(cnt, gen);
    // Stage C: enc3
    conv_body<32, 64, false, false>(x6p, n1, wb_enc3, b_enc3, x6, nsh, NN1 / 64);
    grid_barrier(cnt, gen);
    // Stage D: dec1 (fused unpool: gather x6[n>>2])
    conv_body<64, 32, true, false>(x6, n2, wb_dec1, b_dec1, x7dec, nsh, NN2 / 64);
    grid_barrier(cnt, gen);
    // Stage E: dec2 (fused unpool: gather x7dec[n>>2])
    conv_body<32, 16, true, false>(x7dec, n3, wb_dec2, b_dec2, x8dec, nsh, NN3 / 64);
    grid_barrier(cnt, gen);
    // Stage F: head
    head_body(x8dec, n3, w_head, b_head, out, nsh, wsf);
}

extern "C" void kernel_launch(void* const* d_in, const int* in_sizes, int n_in,
                              void* d_out, int out_size, void* d_ws, size_t ws_size,
                              hipStream_t stream) {
    const float* features = (const float*)d_in[0];
    const int* neighs3 = (const int*)d_in[4];
    const int* neighs2 = (const int*)d_in[5];
    const int* neighs1 = (const int*)d_in[6];
    const float* w_enc1 = (const float*)d_in[7];
    const float* b_enc1 = (const float*)d_in[8];
    const float* w_enc2 = (const float*)d_in[9];
    const float* b_enc2 = (const float*)d_in[10];
    const float* w_enc3 = (const float*)d_in[11];
    const float* b_enc3 = (const float*)d_in[12];
    const float* w_dec1 = (const float*)d_in[13];
    const float* b_dec1 = (const float*)d_in[14];
    const float* w_dec2 = (const float*)d_in[15];
    const float* b_dec2 = (const float*)d_in[16];
    const float* w_head = (const float*)d_in[17];
    const float* b_head = (const float*)d_in[18];

    char* ws = (char*)d_ws;
    size_t off = 0;
    int* bar = (int*)(ws + off); off += 256;
    unsigned short* wb_enc2 = (unsigned short*)(ws + off); off += 4608 * 2;
    unsigned short* wb_enc3 = (unsigned short*)(ws + off); off += 18432 * 2;
    unsigned short* wb_dec1 = (unsigned short*)(ws + off); off += 18432 * 2;
    unsigned short* wb_dec2 = (unsigned short*)(ws + off); off += 4608 * 2;
    unsigned short* x7p   = (unsigned short*)(ws + off); off += (size_t)NN2 * 16 * 2;
    unsigned short* x6p   = (unsigned short*)(ws + off); off += (size_t)NN1 * 32 * 2;
    unsigned short* x6    = (unsigned short*)(ws + off); off += (size_t)NN1 * 64 * 2;
    unsigned short* x7dec = (unsigned short*)(ws + off); off += (size_t)NN2 * 32 * 2;
    unsigned short* x8dec = (unsigned short*)(ws + off); off += (size_t)NN3 * 16 * 2;

    init_barrier_kernel<<<1, 1, 0, stream>>>(bar);
    fused_kernel<<<NBLK, 256, 0, stream>>>(
        features, neighs3, neighs2, neighs1,
        w_enc1, b_enc1, w_enc2, b_enc2, w_enc3, b_enc3,
        w_dec1, b_dec1, w_dec2, b_dec2, w_head, b_head,
        wb_enc2, wb_enc3, wb_dec1, wb_dec2,
        x7p, x6p, x6, x7dec, x8dec,
        (float*)d_out, bar);
}

// Round 5
// 203.817 us; speedup vs baseline: 3.8226x; 3.8226x over previous
//
#include <hip/hip_runtime.h>
#include <stdint.h>

#define NN3 262144
#define NN2 65536
#define NN1 16384

typedef __attribute__((ext_vector_type(8))) __bf16 bf16x8;
typedef __attribute__((ext_vector_type(4))) float floatx4;

static __device__ __forceinline__ float bf2f(unsigned short u) {
    union { unsigned int i; float f; } v; v.i = ((unsigned int)u) << 16; return v.f;
}
static __device__ __forceinline__ unsigned short f2bf(float f) {
    union { float f; unsigned int i; } v; v.f = f;
    unsigned int x = v.i;
    return (unsigned short)((x + 0x7fffu + ((x >> 16) & 1u)) >> 16);
}
static __device__ __forceinline__ bf16x8 zero_bf16x8() {
    bf16x8 z;
#pragma unroll
    for (int i = 0; i < 8; ++i) z[i] = (__bf16)0.0f;
    return z;
}

// ---------------- enc1 + pool1 fused, with weight fp32->bf16 prep folded in ----------------
// Prep outputs (wb_*) are consumed only by LATER dispatches; stream order covers the dependency.
// Pool exploits arange keys: parent(j) = j>>2, so the 4 children of a parent are 4 consecutive
// rows = 4 consecutive lanes. Pool = 2 shuffle-max rounds in fp32 (pre-rounding).
__global__ __launch_bounds__(256) void enc1pool_kernel(
    const float* __restrict__ feat, const int* __restrict__ neigh,
    const float* __restrict__ w, const float* __restrict__ b,
    unsigned short* __restrict__ x7p,
    const float* __restrict__ w_enc2, const float* __restrict__ w_enc3,
    const float* __restrict__ w_dec1, const float* __restrict__ w_dec2,
    unsigned short* __restrict__ wb_enc2, unsigned short* __restrict__ wb_enc3,
    unsigned short* __restrict__ wb_dec1, unsigned short* __restrict__ wb_dec2)
{
    // folded weight prep: 46080 elements over the first 180 blocks
    {
        int g = blockIdx.x * 256 + threadIdx.x;
        if (g < 4608) wb_enc2[g] = f2bf(w_enc2[g]);
        else {
            g -= 4608;
            if (g < 18432) wb_enc3[g] = f2bf(w_enc3[g]);
            else {
                g -= 18432;
                if (g < 18432) wb_dec1[g] = f2bf(w_dec1[g]);
                else { g -= 18432; if (g < 4608) wb_dec2[g] = f2bf(w_dec2[g]); }
            }
        }
    }
    __shared__ float ws[144];
    __shared__ float bs[16];
    __shared__ int nsh[2304];
    int t = threadIdx.x;
    if (t < 144) ws[t] = w[t];
    if (t < 16)  bs[t] = b[t];
    int base = blockIdx.x * 256;
    for (int e = t; e < 2304; e += 256) nsh[e] = neigh[(size_t)base * 9 + e];
    __syncthreads();
    float f[9];
#pragma unroll
    for (int k = 0; k < 9; ++k) { int j = nsh[t * 9 + k]; f[k] = (j < 0) ? 0.0f : feat[j]; }
    float v[16];
#pragma unroll
    for (int co = 0; co < 16; ++co) {
        float a = bs[co];
#pragma unroll
        for (int k = 0; k < 9; ++k) a += f[k] * ws[co * 9 + k];
        v[co] = fmaxf(a, 0.0f);
    }
#pragma unroll
    for (int co = 0; co < 16; ++co) {
        v[co] = fmaxf(v[co], __shfl_xor(v[co], 1));
        v[co] = fmaxf(v[co], __shfl_xor(v[co], 2));
    }
    if ((t & 3) == 0) {
        unsigned int ov[8];
#pragma unroll
        for (int h = 0; h < 8; ++h)
            ov[h] = (unsigned int)f2bf(v[2 * h]) | (((unsigned int)f2bf(v[2 * h + 1])) << 16);
        uint4* dst = (uint4*)(x7p + (size_t)((base + t) >> 2) * 16);
        dst[0] = make_uint4(ov[0], ov[1], ov[2], ov[3]);
        dst[1] = make_uint4(ov[4], ov[5], ov[6], ov[7]);
    }
}

// ---------------- generic MFMA conv ----------------
// One block = 4 waves = 64 rows. A-fragments gathered directly from global (8 contiguous
// k-values lie inside one neighbor row since 8 | CIN).
// SHIFT: gather src[neigh>>2] (fused unpool, arange keys). POOL: epilogue does 4:1 row max
// (a lane's 4 acc elements are rows quad*4..quad*4+3 = one parent's children).
template <int CIN, int COUT, bool SHIFT, bool POOL>
__global__ __launch_bounds__(256) void conv_mfma(
    const unsigned short* __restrict__ src, const int* __restrict__ neigh,
    const unsigned short* __restrict__ wb, const float* __restrict__ bias,
    unsigned short* __restrict__ dst)
{
    constexpr int K  = 9 * CIN;
    constexpr int KT = (K + 31) / 32;
    constexpr int NT = COUT / 16;
    __shared__ int nsh[576];
    int t = threadIdx.x;
    int rowbase = blockIdx.x * 64;
    for (int e = t; e < 576; e += 256) {
        int j = neigh[(size_t)rowbase * 9 + e];
        if (SHIFT) j = (j < 0) ? -1 : (j >> 2);
        nsh[e] = j;
    }
    __syncthreads();
    int lane = t & 63;
    int wave = t >> 6;
    int m    = lane & 15;
    int quad = lane >> 4;
    int mrow = wave * 16 + m;   // row within block's 64
    floatx4 acc[NT];
#pragma unroll
    for (int n = 0; n < NT; ++n) acc[n] = (floatx4){0.f, 0.f, 0.f, 0.f};
#pragma unroll
    for (int kt = 0; kt < KT; ++kt) {
        int k0 = kt * 32 + quad * 8;
        bf16x8 a = zero_bf16x8();
        if (k0 < K) {
            int nb = k0 / CIN;
            int ci = k0 % CIN;
            int j  = nsh[mrow * 9 + nb];
            if (j >= 0) a = *(const bf16x8*)(src + (size_t)j * CIN + ci);
        }
#pragma unroll
        for (int n = 0; n < NT; ++n) {
            bf16x8 bfrag = zero_bf16x8();
            if (k0 < K) bfrag = *(const bf16x8*)(wb + (size_t)(n * 16 + m) * K + k0);
            acc[n] = __builtin_amdgcn_mfma_f32_16x16x32_bf16(a, bfrag, acc[n], 0, 0, 0);
        }
    }
    if (POOL) {
        int p = (rowbase >> 2) + wave * 4 + quad;
#pragma unroll
        for (int n = 0; n < NT; ++n) {
            int cout = n * 16 + m;
            float vm = fmaxf(fmaxf(acc[n][0], acc[n][1]), fmaxf(acc[n][2], acc[n][3]));
            float v  = fmaxf(vm + bias[cout], 0.0f);
            dst[(size_t)p * COUT + cout] = f2bf(v);
        }
    } else {
        int grow = rowbase + wave * 16 + quad * 4;
#pragma unroll
        for (int n = 0; n < NT; ++n) {
            int cout = n * 16 + m;
            float bv = bias[cout];
#pragma unroll
            for (int r = 0; r < 4; ++r) {
                float v = fmaxf(acc[n][r] + bv, 0.0f);
                dst[(size_t)(grow + r) * COUT + cout] = f2bf(v);
            }
        }
    }
}

// ---------------- head: Cin=16 bf16 -> 1 fp32, no relu ----------------
static __device__ __forceinline__ float dot2(unsigned int u, const float* w) {
    return bf2f((unsigned short)(u & 0xffffu)) * w[0] + bf2f((unsigned short)(u >> 16)) * w[1];
}
__global__ __launch_bounds__(256) void head_kernel(
    const unsigned short* __restrict__ x, const int* __restrict__ neigh,
    const float* __restrict__ w, const float* __restrict__ b, float* __restrict__ out)
{
    __shared__ float ws[144];
    __shared__ int nsh[2304];
    int t = threadIdx.x;
    if (t < 144) ws[t] = w[t];
    int base = blockIdx.x * 256;
    for (int e = t; e < 2304; e += 256) nsh[e] = neigh[(size_t)base * 9 + e];
    __syncthreads();
    float acc = b[0];
#pragma unroll
    for (int k = 0; k < 9; ++k) {
        int j = nsh[t * 9 + k];
        if (j >= 0) {
            const uint4* r = (const uint4*)(x + (size_t)j * 16);
            uint4 r0 = r[0], r1 = r[1];
            const float* wp = &ws[k * 16];
            acc += dot2(r0.x, wp)     + dot2(r0.y, wp + 2)  + dot2(r0.z, wp + 4)  + dot2(r0.w, wp + 6);
            acc += dot2(r1.x, wp + 8) + dot2(r1.y, wp + 10) + dot2(r1.z, wp + 12) + dot2(r1.w, wp + 14);
        }
    }
    out[base + t] = acc;
}

extern "C" void kernel_launch(void* const* d_in, const int* in_sizes, int n_in,
                              void* d_out, int out_size, void* d_ws, size_t ws_size,
                              hipStream_t stream) {
    const float* features = (const float*)d_in[0];
    const int* neighs3 = (const int*)d_in[4];
    const int* neighs2 = (const int*)d_in[5];
    const int* neighs1 = (const int*)d_in[6];
    const float* w_enc1 = (const float*)d_in[7];
    const float* b_enc1 = (const float*)d_in[8];
    const float* w_enc2 = (const float*)d_in[9];
    const float* b_enc2 = (const float*)d_in[10];
    const float* w_enc3 = (const float*)d_in[11];
    const float* b_enc3 = (const float*)d_in[12];
    const float* w_dec1 = (const float*)d_in[13];
    const float* b_dec1 = (const float*)d_in[14];
    const float* w_dec2 = (const float*)d_in[15];
    const float* b_dec2 = (const float*)d_in[16];
    const float* w_head = (const float*)d_in[17];
    const float* b_head = (const float*)d_in[18];

    char* ws = (char*)d_ws;
    size_t off = 0;
    unsigned short* wb_enc2 = (unsigned short*)(ws + off); off += 4608 * 2;
    unsigned short* wb_enc3 = (unsigned short*)(ws + off); off += 18432 * 2;
    unsigned short* wb_dec1 = (unsigned short*)(ws + off); off += 18432 * 2;
    unsigned short* wb_dec2 = (unsigned short*)(ws + off); off += 4608 * 2;
    unsigned short* x7p   = (unsigned short*)(ws + off); off += (size_t)NN2 * 16 * 2;
    unsigned short* x6p   = (unsigned short*)(ws + off); off += (size_t)NN1 * 32 * 2;
    unsigned short* x6    = (unsigned short*)(ws + off); off += (size_t)NN1 * 64 * 2;
    unsigned short* x7dec = (unsigned short*)(ws + off); off += (size_t)NN2 * 32 * 2;
    unsigned short* x8dec = (unsigned short*)(ws + off); off += (size_t)NN3 * 16 * 2;

    // 1. enc1 + pool1 (+ folded weight prep): features -> x7p [N2,16]
    enc1pool_kernel<<<NN3 / 256, 256, 0, stream>>>(features, neighs3, w_enc1, b_enc1, x7p,
                                                   w_enc2, w_enc3, w_dec1, w_dec2,
                                                   wb_enc2, wb_enc3, wb_dec1, wb_dec2);
    // 2. enc2 + pool2: x7p -> x6p [N1,32]
    conv_mfma<16, 32, false, true><<<NN2 / 64, 256, 0, stream>>>(x7p, neighs2, wb_enc2, b_enc2, x6p);
    // 3. enc3: x6p -> x6 [N1,64]
    conv_mfma<32, 64, false, false><<<NN1 / 64, 256, 0, stream>>>(x6p, neighs1, wb_enc3, b_enc3, x6);
    // 4. dec1 (fused unpool, gather x6[n>>2]): -> x7dec [N2,32]
    conv_mfma<64, 32, true, false><<<NN2 / 64, 256, 0, stream>>>(x6, neighs2, wb_dec1, b_dec1, x7dec);
    // 5. dec2 (fused unpool, gather x7dec[n>>2]): -> x8dec [N3,16]
    conv_mfma<32, 16, true, false><<<NN3 / 64, 256, 0, stream>>>(x7dec, neighs3, wb_dec2, b_dec2, x8dec);
    // 6. head: x8dec -> out [N3,1]f32
    head_kernel<<<NN3 / 256, 256, 0, stream>>>(x8dec, neighs3, w_head, b_head, (float*)d_out);
}

// Round 6
// 202.163 us; speedup vs baseline: 3.8538x; 1.0082x over previous
//
#include <hip/hip_runtime.h>
#include <stdint.h>

#define NN3 262144
#define NN2 65536
#define NN1 16384

typedef __attribute__((ext_vector_type(8))) __bf16 bf16x8;
typedef __attribute__((ext_vector_type(4))) float floatx4;

static __device__ __forceinline__ float bf2f(unsigned short u) {
    union { unsigned int i; float f; } v; v.i = ((unsigned int)u) << 16; return v.f;
}
static __device__ __forceinline__ unsigned short f2bf(float f) {
    union { float f; unsigned int i; } v; v.f = f;
    unsigned int x = v.i;
    return (unsigned short)((x + 0x7fffu + ((x >> 16) & 1u)) >> 16);
}
static __device__ __forceinline__ bf16x8 zero_bf16x8() {
    bf16x8 z;
#pragma unroll
    for (int i = 0; i < 8; ++i) z[i] = (__bf16)0.0f;
    return z;
}

// ---------------- enc1 + pool1 fused, with weight fp32->bf16 prep folded in ----------------
__global__ __launch_bounds__(256) void enc1pool_kernel(
    const float* __restrict__ feat, const int* __restrict__ neigh,
    const float* __restrict__ w, const float* __restrict__ b,
    unsigned short* __restrict__ x7p,
    const float* __restrict__ w_enc2, const float* __restrict__ w_enc3,
    const float* __restrict__ w_dec1, const float* __restrict__ w_dec2,
    unsigned short* __restrict__ wb_enc2, unsigned short* __restrict__ wb_enc3,
    unsigned short* __restrict__ wb_dec1, unsigned short* __restrict__ wb_dec2)
{
    // folded weight prep: 46080 elements over the first 180 blocks
    {
        int g = blockIdx.x * 256 + threadIdx.x;
        if (g < 4608) wb_enc2[g] = f2bf(w_enc2[g]);
        else {
            g -= 4608;
            if (g < 18432) wb_enc3[g] = f2bf(w_enc3[g]);
            else {
                g -= 18432;
                if (g < 18432) wb_dec1[g] = f2bf(w_dec1[g]);
                else { g -= 18432; if (g < 4608) wb_dec2[g] = f2bf(w_dec2[g]); }
            }
        }
    }
    __shared__ float ws[144];
    __shared__ float bs[16];
    __shared__ int nsh[2304];
    int t = threadIdx.x;
    if (t < 144) ws[t] = w[t];
    if (t < 16)  bs[t] = b[t];
    int base = blockIdx.x * 256;
    for (int e = t; e < 2304; e += 256)
        nsh[e] = __builtin_nontemporal_load(&neigh[(size_t)base * 9 + e]);
    __syncthreads();
    float f[9];
#pragma unroll
    for (int k = 0; k < 9; ++k) { int j = nsh[t * 9 + k]; f[k] = (j < 0) ? 0.0f : feat[j]; }
    float v[16];
#pragma unroll
    for (int co = 0; co < 16; ++co) {
        float a = bs[co];
#pragma unroll
        for (int k = 0; k < 9; ++k) a += f[k] * ws[co * 9 + k];
        v[co] = fmaxf(a, 0.0f);
    }
#pragma unroll
    for (int co = 0; co < 16; ++co) {
        v[co] = fmaxf(v[co], __shfl_xor(v[co], 1));
        v[co] = fmaxf(v[co], __shfl_xor(v[co], 2));
    }
    if ((t & 3) == 0) {
        unsigned int ov[8];
#pragma unroll
        for (int h = 0; h < 8; ++h)
            ov[h] = (unsigned int)f2bf(v[2 * h]) | (((unsigned int)f2bf(v[2 * h + 1])) << 16);
        uint4* dst = (uint4*)(x7p + (size_t)((base + t) >> 2) * 16);
        dst[0] = make_uint4(ov[0], ov[1], ov[2], ov[3]);
        dst[1] = make_uint4(ov[4], ov[5], ov[6], ov[7]);
    }
}

// ---------------- generic MFMA conv, TILES row-tiles of 64 per block ----------------
// More tiles => more independent A-gathers in flight per wave (TILES*KT of 16B each).
// SHIFT: gather src[neigh>>2] (fused unpool). POOL: 4:1 row-max epilogue.
template <int CIN, int COUT, bool SHIFT, bool POOL, int TILES>
__global__ __launch_bounds__(256) void conv_mfma(
    const unsigned short* __restrict__ src, const int* __restrict__ neigh,
    const unsigned short* __restrict__ wb, const float* __restrict__ bias,
    unsigned short* __restrict__ dst)
{
    constexpr int K  = 9 * CIN;
    constexpr int KT = (K + 31) / 32;
    constexpr int NT = COUT / 16;
    __shared__ int nsh[576 * TILES];
    int t = threadIdx.x;
    int rowbase = blockIdx.x * (64 * TILES);
    for (int e = t; e < 576 * TILES; e += 256) {
        int j = __builtin_nontemporal_load(&neigh[(size_t)rowbase * 9 + e]);
        if (SHIFT) j = (j < 0) ? -1 : (j >> 2);
        nsh[e] = j;
    }
    __syncthreads();
    int lane = t & 63;
    int wave = t >> 6;
    int m    = lane & 15;
    int quad = lane >> 4;
    int mrow9 = (wave * 16 + m) * 9;
    floatx4 acc[TILES][NT];
#pragma unroll
    for (int tl = 0; tl < TILES; ++tl)
#pragma unroll
        for (int n = 0; n < NT; ++n) acc[tl][n] = (floatx4){0.f, 0.f, 0.f, 0.f};
    for (int kt = 0; kt < KT; ++kt) {
        int k0 = kt * 32 + quad * 8;
        bf16x8 a[TILES];
#pragma unroll
        for (int tl = 0; tl < TILES; ++tl) {
            a[tl] = zero_bf16x8();
            if (k0 < K) {
                int nb = k0 / CIN;
                int ci = k0 % CIN;
                int j  = nsh[tl * 576 + mrow9 + nb];
                if (j >= 0) a[tl] = *(const bf16x8*)(src + (size_t)j * CIN + ci);
            }
        }
#pragma unroll
        for (int n = 0; n < NT; ++n) {
            bf16x8 bfrag = zero_bf16x8();
            if (k0 < K) bfrag = *(const bf16x8*)(wb + (size_t)(n * 16 + m) * K + k0);
#pragma unroll
            for (int tl = 0; tl < TILES; ++tl)
                acc[tl][n] = __builtin_amdgcn_mfma_f32_16x16x32_bf16(a[tl], bfrag, acc[tl][n], 0, 0, 0);
        }
    }
#pragma unroll
    for (int tl = 0; tl < TILES; ++tl) {
        int tbase = rowbase + tl * 64;
        if (POOL) {
            int p = (tbase >> 2) + wave * 4 + quad;
#pragma unroll
            for (int n = 0; n < NT; ++n) {
                int cout = n * 16 + m;
                float vm = fmaxf(fmaxf(acc[tl][n][0], acc[tl][n][1]), fmaxf(acc[tl][n][2], acc[tl][n][3]));
                float v  = fmaxf(vm + bias[cout], 0.0f);
                dst[(size_t)p * COUT + cout] = f2bf(v);
            }
        } else {
            int grow = tbase + wave * 16 + quad * 4;
#pragma unroll
            for (int n = 0; n < NT; ++n) {
                int cout = n * 16 + m;
                float bv = bias[cout];
#pragma unroll
                for (int r = 0; r < 4; ++r) {
                    float v = fmaxf(acc[tl][n][r] + bv, 0.0f);
                    dst[(size_t)(grow + r) * COUT + cout] = f2bf(v);
                }
            }
        }
    }
}

// ---------------- head: Cin=16 bf16 -> 1 fp32, no relu; 2 rows per thread ----------------
static __device__ __forceinline__ float dot2(unsigned int u, const float* w) {
    return bf2f((unsigned short)(u & 0xffffu)) * w[0] + bf2f((unsigned short)(u >> 16)) * w[1];
}
__global__ __launch_bounds__(256) void head_kernel(
    const unsigned short* __restrict__ x, const int* __restrict__ neigh,
    const float* __restrict__ w, const float* __restrict__ b, float* __restrict__ out)
{
    __shared__ float ws[144];
    __shared__ int nsh[4608];
    int t = threadIdx.x;
    if (t < 144) ws[t] = w[t];
    int base = blockIdx.x * 512;
    for (int e = t; e < 4608; e += 256)
        nsh[e] = __builtin_nontemporal_load(&neigh[(size_t)base * 9 + e]);
    __syncthreads();
    float acc0 = b[0], acc1 = b[0];
#pragma unroll
    for (int k = 0; k < 9; ++k) {
        int j0 = nsh[t * 9 + k];
        int j1 = nsh[(256 + t) * 9 + k];
        const float* wp = &ws[k * 16];
        if (j0 >= 0) {
            const uint4* r = (const uint4*)(x + (size_t)j0 * 16);
            uint4 r0 = r[0], r1 = r[1];
            acc0 += dot2(r0.x, wp)     + dot2(r0.y, wp + 2)  + dot2(r0.z, wp + 4)  + dot2(r0.w, wp + 6);
            acc0 += dot2(r1.x, wp + 8) + dot2(r1.y, wp + 10) + dot2(r1.z, wp + 12) + dot2(r1.w, wp + 14);
        }
        if (j1 >= 0) {
            const uint4* r = (const uint4*)(x + (size_t)j1 * 16);
            uint4 r0 = r[0], r1 = r[1];
            acc1 += dot2(r0.x, wp)     + dot2(r0.y, wp + 2)  + dot2(r0.z, wp + 4)  + dot2(r0.w, wp + 6);
            acc1 += dot2(r1.x, wp + 8) + dot2(r1.y, wp + 10) + dot2(r1.z, wp + 12) + dot2(r1.w, wp + 14);
        }
    }
    __builtin_nontemporal_store(acc0, &out[base + t]);
    __builtin_nontemporal_store(acc1, &out[base + 256 + t]);
}

extern "C" void kernel_launch(void* const* d_in, const int* in_sizes, int n_in,
                              void* d_out, int out_size, void* d_ws, size_t ws_size,
                              hipStream_t stream) {
    const float* features = (const float*)d_in[0];
    const int* neighs3 = (const int*)d_in[4];
    const int* neighs2 = (const int*)d_in[5];
    const int* neighs1 = (const int*)d_in[6];
    const float* w_enc1 = (const float*)d_in[7];
    const float* b_enc1 = (const float*)d_in[8];
    const float* w_enc2 = (const float*)d_in[9];
    const float* b_enc2 = (const float*)d_in[10];
    const float* w_enc3 = (const float*)d_in[11];
    const float* b_enc3 = (const float*)d_in[12];
    const float* w_dec1 = (const float*)d_in[13];
    const float* b_dec1 = (const float*)d_in[14];
    const float* w_dec2 = (const float*)d_in[15];
    const float* b_dec2 = (const float*)d_in[16];
    const float* w_head = (const float*)d_in[17];
    const float* b_head = (const float*)d_in[18];

    char* ws = (char*)d_ws;
    size_t off = 0;
    unsigned short* wb_enc2 = (unsigned short*)(ws + off); off += 4608 * 2;
    unsigned short* wb_enc3 = (unsigned short*)(ws + off); off += 18432 * 2;
    unsigned short* wb_dec1 = (unsigned short*)(ws + off); off += 18432 * 2;
    unsigned short* wb_dec2 = (unsigned short*)(ws + off); off += 4608 * 2;
    unsigned short* x7p   = (unsigned short*)(ws + off); off += (size_t)NN2 * 16 * 2;
    unsigned short* x6p   = (unsigned short*)(ws + off); off += (size_t)NN1 * 32 * 2;
    unsigned short* x6    = (unsigned short*)(ws + off); off += (size_t)NN1 * 64 * 2;
    unsigned short* x7dec = (unsigned short*)(ws + off); off += (size_t)NN2 * 32 * 2;
    unsigned short* x8dec = (unsigned short*)(ws + off); off += (size_t)NN3 * 16 * 2;

    // 1. enc1 + pool1 (+ folded weight prep): features -> x7p [N2,16]
    enc1pool_kernel<<<NN3 / 256, 256, 0, stream>>>(features, neighs3, w_enc1, b_enc1, x7p,
                                                   w_enc2, w_enc3, w_dec1, w_dec2,
                                                   wb_enc2, wb_enc3, wb_dec1, wb_dec2);
    // 2. enc2 + pool2: x7p -> x6p [N1,32]   (2 tiles/block)
    conv_mfma<16, 32, false, true, 2><<<NN2 / 128, 256, 0, stream>>>(x7p, neighs2, wb_enc2, b_enc2, x6p);
    // 3. enc3: x6p -> x6 [N1,64]            (1 tile/block, small)
    conv_mfma<32, 64, false, false, 1><<<NN1 / 64, 256, 0, stream>>>(x6p, neighs1, wb_enc3, b_enc3, x6);
    // 4. dec1 (fused unpool, gather x6[n>>2]): -> x7dec [N2,32]   (2 tiles/block)
    conv_mfma<64, 32, true, false, 2><<<NN2 / 128, 256, 0, stream>>>(x6, neighs2, wb_dec1, b_dec1, x7dec);
    // 5. dec2 (fused unpool, gather x7dec[n>>2]): -> x8dec [N3,16]  (4 tiles/block)
    conv_mfma<32, 16, true, false, 4><<<NN3 / 256, 256, 0, stream>>>(x7dec, neighs3, wb_dec2, b_dec2, x8dec);
    // 6. head: x8dec -> out [N3,1]f32       (2 rows/thread)
    head_kernel<<<NN3 / 512, 256, 0, stream>>>(x8dec, neighs3, w_head, b_head, (float*)d_out);
}